// Round 1
// baseline (236.901 us; speedup 1.0000x reference)
//
#include <hip/hip_runtime.h>
#include <hip/hip_bf16.h>

#define NNODE 100000
#define CIN   64
#define CHID  64
#define NREL  8
#define KTOT  512      // NREL * CIN
#define NGRP  6250     // NNODE / 16

typedef __attribute__((ext_vector_type(8))) short bf16x8;
typedef __attribute__((ext_vector_type(4))) float f32x4;

__device__ __forceinline__ unsigned short f2bf(float f) {
    __hip_bfloat16 h = __float2bfloat16(f);
    return __builtin_bit_cast(unsigned short, h);
}
__device__ __forceinline__ float bf2f(unsigned short u) {
    unsigned int v = ((unsigned int)u) << 16;
    return __builtin_bit_cast(float, v);
}

// ---- prep: x (f32) -> xb (bf16) ----
__global__ void k_prep_x(const float* __restrict__ x, unsigned short* __restrict__ xb) {
    int i = (blockIdx.x * 256 + threadIdx.x) * 4;
    if (i >= NNODE * CIN) return;
    float4 v = *reinterpret_cast<const float4*>(x + i);
    ushort4 o;
    o.x = f2bf(v.x); o.y = f2bf(v.y); o.z = f2bf(v.z); o.w = f2bf(v.w);
    *reinterpret_cast<ushort4*>(xb + i) = o;
}

// ---- prep: W (f32 [8][64][64]) -> B-fragment-ordered bf16 for mfma_16x16x32 ----
// tile = kt*4+nt (kt in 0..15, nt in 0..3); within tile, lane l holds 8 bf16:
// B[k = kt*32 + (l>>4)*8 + j][col = nt*16 + (l&15)], k = r*64 + ki (flat W index).
__global__ void k_prep_w(const float* __restrict__ W, unsigned short* __restrict__ wf) {
    int tid = blockIdx.x * 256 + threadIdx.x;
    if (tid >= 64 * 64) return;
    int tile = tid >> 6;
    int lane = tid & 63;
    int kt = tile >> 2, nt = tile & 3;
    int kbase = kt * 32 + (lane >> 4) * 8;
    int col = nt * 16 + (lane & 15);
    unsigned short v[8];
#pragma unroll
    for (int j = 0; j < 8; ++j) {
        int k = kbase + j;                  // 0..511, == r*64 + ki
        v[j] = f2bf(W[k * 64 + col]);       // W flat [(r*64+ki)*64 + col]
    }
    ushort4* dst = reinterpret_cast<ushort4*>(wf + (size_t)tid * 8);
    ushort4 lo, hi;
    lo.x = v[0]; lo.y = v[1]; lo.z = v[2]; lo.w = v[3];
    hi.x = v[4]; hi.y = v[5]; hi.z = v[6]; hi.w = v[7];
    dst[0] = lo; dst[1] = hi;
}

// ---- main: gather per-relation sums -> LDS S-tile -> MFMA with W -> epilogue ----
__launch_bounds__(256, 2)
__global__ void k_main(const unsigned short* __restrict__ xb,
                       const bf16x8* __restrict__ wf,
                       const int* __restrict__ ptr,
                       const int* __restrict__ idx,
                       const int* __restrict__ et,
                       const int* __restrict__ hmap,
                       const float* __restrict__ hbuf,
                       float* __restrict__ out) {
    // per-wave S tile: 16 nodes x 512 (bf16) = 16 KB, XOR-swizzled
    __shared__ __align__(16) unsigned short S[4][8192];

    int wave = __builtin_amdgcn_readfirstlane((int)(threadIdx.x >> 6));
    int lane = threadIdx.x & 63;
    int group = blockIdx.x * 4 + wave;
    if (group >= NGRP) return;
    int n0 = group * 16;
    char* sb = reinterpret_cast<char*>(&S[wave][0]);

    // ---------- gather/accumulate phase ----------
    int l16 = lane & 15;
    for (int nn = 0; nn < 16; ++nn) {
        int node = n0 + nn;
        int eb = ptr[node], en = ptr[node + 1];
        float s0=0.f,s1=0.f,s2=0.f,s3=0.f,s4=0.f,s5=0.f,s6=0.f,s7=0.f;
        for (int e = eb; e < en; e += 16) {
            int m = en - e;
            int vidx = 0, vtyp = 0;
            if (l16 < m) { vidx = idx[e + l16]; vtyp = et[e + l16]; }
            if (m >= 16) {
                unsigned short xv[16];
#pragma unroll
                for (int ee = 0; ee < 16; ++ee) {
                    int src = __builtin_amdgcn_readlane(vidx, ee);
                    xv[ee] = xb[src * 64 + lane];
                }
#pragma unroll
                for (int ee = 0; ee < 16; ++ee) {
                    int t = __builtin_amdgcn_readlane(vtyp, ee);
                    float v = bf2f(xv[ee]);
                    if      (t == 0) s0 += v;
                    else if (t == 1) s1 += v;
                    else if (t == 2) s2 += v;
                    else if (t == 3) s3 += v;
                    else if (t == 4) s4 += v;
                    else if (t == 5) s5 += v;
                    else if (t == 6) s6 += v;
                    else             s7 += v;
                }
            } else {
                for (int ee = 0; ee < m; ++ee) {
                    int src = __builtin_amdgcn_readlane(vidx, ee);
                    int t   = __builtin_amdgcn_readlane(vtyp, ee);
                    float v = bf2f(xb[src * 64 + lane]);
                    if      (t == 0) s0 += v;
                    else if (t == 1) s1 += v;
                    else if (t == 2) s2 += v;
                    else if (t == 3) s3 += v;
                    else if (t == 4) s4 += v;
                    else if (t == 5) s5 += v;
                    else if (t == 6) s6 += v;
                    else             s7 += v;
                }
            }
        }
        // store S row nn as bf16, swizzled: byte ^= ((row&7)<<4)
        unsigned int xr = ((unsigned int)(nn & 7)) << 4;
        unsigned int rb = (unsigned int)nn * 1024u;
        float sv[8] = {s0,s1,s2,s3,s4,s5,s6,s7};
#pragma unroll
        for (int r = 0; r < 8; ++r) {
            unsigned int byte = (rb + (unsigned int)r * 128u + (unsigned int)lane * 2u) ^ xr;
            *reinterpret_cast<unsigned short*>(sb + byte) = f2bf(sv[r]);
        }
    }

    // ---------- MFMA phase: [16 nodes x 512] @ [512 x 64] ----------
    f32x4 acc0 = {0.f,0.f,0.f,0.f};
    f32x4 acc1 = {0.f,0.f,0.f,0.f};
    f32x4 acc2 = {0.f,0.f,0.f,0.f};
    f32x4 acc3 = {0.f,0.f,0.f,0.f};
    unsigned int arow  = (unsigned int)(lane & 15);
    unsigned int abase = arow * 1024u + (unsigned int)((lane >> 4) * 16);
    unsigned int axor  = (arow & 7u) << 4;
#pragma unroll 2
    for (int kt = 0; kt < 16; ++kt) {
        unsigned int abyte = (abase + (unsigned int)kt * 64u) ^ axor;
        bf16x8 a = *reinterpret_cast<const bf16x8*>(sb + abyte);
        bf16x8 b0 = wf[(kt * 4 + 0) * 64 + lane];
        bf16x8 b1 = wf[(kt * 4 + 1) * 64 + lane];
        bf16x8 b2 = wf[(kt * 4 + 2) * 64 + lane];
        bf16x8 b3 = wf[(kt * 4 + 3) * 64 + lane];
        acc0 = __builtin_amdgcn_mfma_f32_16x16x32_bf16(a, b0, acc0, 0, 0, 0);
        acc1 = __builtin_amdgcn_mfma_f32_16x16x32_bf16(a, b1, acc1, 0, 0, 0);
        acc2 = __builtin_amdgcn_mfma_f32_16x16x32_bf16(a, b2, acc2, 0, 0, 0);
        acc3 = __builtin_amdgcn_mfma_f32_16x16x32_bf16(a, b3, acc3, 0, 0, 0);
    }

    // ---------- epilogue: /deg, history overwrite, write both outputs ----------
    int colb  = lane & 15;
    int rquad = (lane >> 4) * 4;
    f32x4 accs[4] = {acc0, acc1, acc2, acc3};
#pragma unroll
    for (int nt = 0; nt < 4; ++nt) {
        int col = nt * 16 + colb;
#pragma unroll
        for (int j = 0; j < 4; ++j) {
            int node = n0 + rquad + j;
            float invd = 1.0f / (float)(ptr[node + 1] - ptr[node]);
            float v = accs[nt][j] * invd;
            if (hmap[node] != -1) v = hbuf[node * 64 + col];
            out[node * 64 + col] = v;
            out[NNODE * 64 + node * 64 + col] = v;
        }
    }
}

extern "C" void kernel_launch(void* const* d_in, const int* in_sizes, int n_in,
                              void* d_out, int out_size, void* d_ws, size_t ws_size,
                              hipStream_t stream) {
    (void)in_sizes; (void)n_in; (void)out_size; (void)ws_size;
    const float* x    = (const float*)d_in[0];
    const float* W    = (const float*)d_in[1];
    const int*   ptr  = (const int*)d_in[2];
    const int*   idx  = (const int*)d_in[3];
    const int*   et   = (const int*)d_in[4];
    const int*   hmap = (const int*)d_in[6];
    const float* hbuf = (const float*)d_in[7];
    float* out = (float*)d_out;

    unsigned short* xb = (unsigned short*)d_ws;                                   // 12.8 MB
    unsigned short* wfu = (unsigned short*)((char*)d_ws + (size_t)NNODE * CIN * 2); // 64 KB

    k_prep_x<<<dim3((NNODE * CIN / 4 + 255) / 256), dim3(256), 0, stream>>>(x, xb);
    k_prep_w<<<dim3(16), dim3(256), 0, stream>>>(W, wfu);
    k_main<<<dim3((NGRP + 3) / 4), dim3(256), 0, stream>>>(
        xb, (const bf16x8*)wfu, ptr, idx, et, hmap, hbuf, out);
}

// Round 2
// 90.349 us; speedup vs baseline: 2.6221x; 2.6221x over previous
//
#include <hip/hip_runtime.h>
#include <hip/hip_bf16.h>

#define NNODE 100000
#define CIN   64
#define CHID  64
#define NREL  8
#define KTOT  512      // NREL * CIN, flat k = ki*8 + r  (ki = input channel, r = relation)
#define NGRP  6250     // NNODE / 16

typedef __attribute__((ext_vector_type(8))) short bf16x8;
typedef __attribute__((ext_vector_type(4))) float f32x4;

__device__ __forceinline__ unsigned short f2bf(float f) {
    __hip_bfloat16 h = __float2bfloat16(f);
    return __builtin_bit_cast(unsigned short, h);
}
__device__ __forceinline__ float bf2f(unsigned short u) {
    unsigned int v = ((unsigned int)u) << 16;
    return __builtin_bit_cast(float, v);
}

// ---- prep: x (f32) -> xb (bf16) ----
__global__ void k_prep_x(const float* __restrict__ x, unsigned short* __restrict__ xb) {
    int i = (blockIdx.x * 256 + threadIdx.x) * 4;
    if (i >= NNODE * CIN) return;
    float4 v = *reinterpret_cast<const float4*>(x + i);
    ushort4 o;
    o.x = f2bf(v.x); o.y = f2bf(v.y); o.z = f2bf(v.z); o.w = f2bf(v.w);
    *reinterpret_cast<ushort4*>(xb + i) = o;
}

// ---- prep: W (f32 [8][64][64]) -> B-fragment-ordered bf16 for mfma_16x16x32 ----
// flat k = ki*8 + r  =>  W element = W[r][ki][col] = Wflat[(k&7)*4096 + (k>>3)*64 + col]
// tile = kt*4+nt; lane l holds B[k = kt*32 + (l>>4)*8 + j][col = nt*16 + (l&15)], j=0..7
__global__ void k_prep_w(const float* __restrict__ W, unsigned short* __restrict__ wf) {
    int tid = blockIdx.x * 256 + threadIdx.x;
    if (tid >= 64 * 64) return;
    int tile = tid >> 6;
    int lane = tid & 63;
    int kt = tile >> 2, nt = tile & 3;
    int kbase = kt * 32 + (lane >> 4) * 8;
    int col = nt * 16 + (lane & 15);
    unsigned short v[8];
#pragma unroll
    for (int j = 0; j < 8; ++j) {
        int k = kbase + j;                  // 0..511, == ki*8 + r
        int r = k & 7, ki = k >> 3;
        v[j] = f2bf(W[r * 4096 + ki * 64 + col]);
    }
    ushort4* dst = reinterpret_cast<ushort4*>(wf + (size_t)tid * 8);
    ushort4 lo, hi;
    lo.x = v[0]; lo.y = v[1]; lo.z = v[2]; lo.w = v[3];
    hi.x = v[4]; hi.y = v[5]; hi.z = v[6]; hi.w = v[7];
    dst[0] = lo; dst[1] = hi;
}

// ---- main: block = 4 waves share one 16-node group ----
// wave w gathers nodes n0+4w..n0+4w+3 into shared S[16][512]; barrier;
// wave w computes output N-slice cols [16w, 16w+16) via 16 MFMAs.
__launch_bounds__(256, 8)
__global__ void k_main(const unsigned short* __restrict__ xb,
                       const bf16x8* __restrict__ wf,
                       const int* __restrict__ ptr,
                       const int* __restrict__ idx,
                       const int* __restrict__ et,
                       const int* __restrict__ hmap,
                       const float* __restrict__ hbuf,
                       float* __restrict__ out) {
    // shared S tile: 16 nodes x 512 k (bf16) = 16 KB, XOR-swizzled
    __shared__ __align__(16) unsigned short S[8192];

    int wave = __builtin_amdgcn_readfirstlane((int)(threadIdx.x >> 6));
    int lane = threadIdx.x & 63;
    int group = blockIdx.x;
    int n0 = group * 16;
    char* sb = reinterpret_cast<char*>(&S[0]);

    // ---------- gather/accumulate phase: 4 nodes per wave ----------
    int l16 = lane & 15;
    for (int nn = 0; nn < 4; ++nn) {
        int row = wave * 4 + nn;            // 0..15 within the group
        int node = n0 + row;
        int eb = ptr[node], en = ptr[node + 1];
        float s0=0.f,s1=0.f,s2=0.f,s3=0.f,s4=0.f,s5=0.f,s6=0.f,s7=0.f;
        for (int e = eb; e < en; e += 16) {
            int m = en - e; if (m > 16) m = 16;
            int vidx = 0, vtyp = 0;
            if (l16 < m) { vidx = idx[e + l16]; vtyp = et[e + l16]; }
#pragma unroll
            for (int b = 0; b < 2; ++b) {
                int base = b * 8;
                if (m >= base + 8) {
                    unsigned short xv[8];
#pragma unroll
                    for (int ee = 0; ee < 8; ++ee) {
                        int src = __builtin_amdgcn_readlane(vidx, base + ee);
                        xv[ee] = xb[src * 64 + lane];
                    }
#pragma unroll
                    for (int ee = 0; ee < 8; ++ee) {
                        int t = __builtin_amdgcn_readlane(vtyp, base + ee);
                        float v = bf2f(xv[ee]);
                        if      (t == 0) s0 += v;
                        else if (t == 1) s1 += v;
                        else if (t == 2) s2 += v;
                        else if (t == 3) s3 += v;
                        else if (t == 4) s4 += v;
                        else if (t == 5) s5 += v;
                        else if (t == 6) s6 += v;
                        else             s7 += v;
                    }
                } else {
                    for (int ee = base; ee < m; ++ee) {
                        int src = __builtin_amdgcn_readlane(vidx, ee);
                        int t   = __builtin_amdgcn_readlane(vtyp, ee);
                        float v = bf2f(xb[src * 64 + lane]);
                        if      (t == 0) s0 += v;
                        else if (t == 1) s1 += v;
                        else if (t == 2) s2 += v;
                        else if (t == 3) s3 += v;
                        else if (t == 4) s4 += v;
                        else if (t == 5) s5 += v;
                        else if (t == 6) s6 += v;
                        else             s7 += v;
                    }
                }
            }
        }
        // k = ki*8 + r: lane (=ki) owns 8 consecutive k -> one 16B swizzled write
        bf16x8 pk;
        pk[0] = (short)f2bf(s0); pk[1] = (short)f2bf(s1);
        pk[2] = (short)f2bf(s2); pk[3] = (short)f2bf(s3);
        pk[4] = (short)f2bf(s4); pk[5] = (short)f2bf(s5);
        pk[6] = (short)f2bf(s6); pk[7] = (short)f2bf(s7);
        unsigned int byte = ((unsigned int)row * 1024u + (unsigned int)lane * 16u)
                            ^ (((unsigned int)(row & 7)) << 4);
        *reinterpret_cast<bf16x8*>(sb + byte) = pk;
    }
    __syncthreads();

    // ---------- MFMA phase: wave handles N-slice nt = wave ----------
    int nt = wave;
    f32x4 acc = {0.f,0.f,0.f,0.f};
    unsigned int arow  = (unsigned int)(lane & 15);
    unsigned int abase = arow * 1024u + (unsigned int)((lane >> 4) * 16);
    unsigned int axor  = (arow & 7u) << 4;
#pragma unroll 4
    for (int kt = 0; kt < 16; ++kt) {
        unsigned int abyte = (abase + (unsigned int)kt * 64u) ^ axor;
        bf16x8 a = *reinterpret_cast<const bf16x8*>(sb + abyte);
        bf16x8 b = wf[(kt * 4 + nt) * 64 + lane];
        acc = __builtin_amdgcn_mfma_f32_16x16x32_bf16(a, b, acc, 0, 0, 0);
    }

    // ---------- epilogue: /deg, history overwrite, write both outputs ----------
    int col   = nt * 16 + (lane & 15);
    int rquad = (lane >> 4) * 4;
#pragma unroll
    for (int j = 0; j < 4; ++j) {
        int node = n0 + rquad + j;
        float invd = 1.0f / (float)(ptr[node + 1] - ptr[node]);
        float v = acc[j] * invd;
        if (hmap[node] != -1) v = hbuf[node * 64 + col];
        out[node * 64 + col] = v;
        out[NNODE * 64 + node * 64 + col] = v;
    }
}

extern "C" void kernel_launch(void* const* d_in, const int* in_sizes, int n_in,
                              void* d_out, int out_size, void* d_ws, size_t ws_size,
                              hipStream_t stream) {
    (void)in_sizes; (void)n_in; (void)out_size; (void)ws_size;
    const float* x    = (const float*)d_in[0];
    const float* W    = (const float*)d_in[1];
    const int*   ptr  = (const int*)d_in[2];
    const int*   idx  = (const int*)d_in[3];
    const int*   et   = (const int*)d_in[4];
    const int*   hmap = (const int*)d_in[6];
    const float* hbuf = (const float*)d_in[7];
    float* out = (float*)d_out;

    unsigned short* xb = (unsigned short*)d_ws;                                     // 12.8 MB
    unsigned short* wfu = (unsigned short*)((char*)d_ws + (size_t)NNODE * CIN * 2); // 64 KB

    k_prep_x<<<dim3((NNODE * CIN / 4 + 255) / 256), dim3(256), 0, stream>>>(x, xb);
    k_prep_w<<<dim3(16), dim3(256), 0, stream>>>(W, wfu);
    k_main<<<dim3(NGRP), dim3(256), 0, stream>>>(
        xb, (const bf16x8*)wfu, ptr, idx, et, hmap, hbuf, out);
}

// Round 3
// 83.362 us; speedup vs baseline: 2.8418x; 1.0838x over previous
//
#include <hip/hip_runtime.h>
#include <hip/hip_bf16.h>

#define NNODE 100000
#define CIN   64
#define CHID  64
#define NREL  8
#define KTOT  512      // NREL * CIN, flat k = ki*8 + r  (ki = input channel, r = relation)
#define NGRP  6250     // NNODE / 16

typedef __attribute__((ext_vector_type(8))) short bf16x8;
typedef __attribute__((ext_vector_type(4))) float f32x4;

__device__ __forceinline__ unsigned short f2bf(float f) {
    __hip_bfloat16 h = __float2bfloat16(f);
    return __builtin_bit_cast(unsigned short, h);
}
__device__ __forceinline__ float bf2f(unsigned short u) {
    unsigned int v = ((unsigned int)u) << 16;
    return __builtin_bit_cast(float, v);
}

// ---- prep: x (f32) -> xb (bf16) ----
__global__ void k_prep_x(const float* __restrict__ x, unsigned short* __restrict__ xb) {
    int i = (blockIdx.x * 256 + threadIdx.x) * 4;
    if (i >= NNODE * CIN) return;
    float4 v = *reinterpret_cast<const float4*>(x + i);
    ushort4 o;
    o.x = f2bf(v.x); o.y = f2bf(v.y); o.z = f2bf(v.z); o.w = f2bf(v.w);
    *reinterpret_cast<ushort4*>(xb + i) = o;
}

// ---- prep: W (f32 [8][64][64]) -> B-fragment-ordered bf16 for mfma_16x16x32 ----
// flat k = ki*8 + r  =>  W element = W[r][ki][col] = Wflat[(k&7)*4096 + (k>>3)*64 + col]
// tile = kt*4+nt; lane l holds B[k = kt*32 + (l>>4)*8 + j][col = nt*16 + (l&15)], j=0..7
__global__ void k_prep_w(const float* __restrict__ W, unsigned short* __restrict__ wf) {
    int tid = blockIdx.x * 256 + threadIdx.x;
    if (tid >= 64 * 64) return;
    int tile = tid >> 6;
    int lane = tid & 63;
    int kt = tile >> 2, nt = tile & 3;
    int kbase = kt * 32 + (lane >> 4) * 8;
    int col = nt * 16 + (lane & 15);
    unsigned short v[8];
#pragma unroll
    for (int j = 0; j < 8; ++j) {
        int k = kbase + j;                  // 0..511, == ki*8 + r
        int r = k & 7, ki = k >> 3;
        v[j] = f2bf(W[r * 4096 + ki * 64 + col]);
    }
    ushort4* dst = reinterpret_cast<ushort4*>(wf + (size_t)tid * 8);
    ushort4 lo, hi;
    lo.x = v[0]; lo.y = v[1]; lo.z = v[2]; lo.w = v[3];
    hi.x = v[4]; hi.y = v[5]; hi.z = v[6]; hi.w = v[7];
    dst[0] = lo; dst[1] = hi;
}

// ---- main: block = 4 waves share one 16-node group ----
// wave w gathers nodes n0+4w..n0+4w+3 into shared S[16][512] (bf16, swizzled);
// fast path (deg==16 for all 4 nodes): one wave-load of 64 idx + 64 types,
// then 16-deep staged gather loads, software-pipelined across nodes.
__launch_bounds__(256, 8)
__global__ void k_main(const unsigned short* __restrict__ xb,
                       const bf16x8* __restrict__ wf,
                       const int* __restrict__ ptr,
                       const int* __restrict__ idx,
                       const int* __restrict__ et,
                       const int* __restrict__ hmap,
                       const float* __restrict__ hbuf,
                       float* __restrict__ out) {
    __shared__ __align__(16) unsigned short S[8192];   // 16 rows x 512 k (bf16), 16 KB

    int wave = __builtin_amdgcn_readfirstlane((int)(threadIdx.x >> 6));
    int lane = threadIdx.x & 63;
    int n0 = blockIdx.x * 16;
    int nbase = n0 + wave * 4;
    char* sb = reinterpret_cast<char*>(&S[0]);

    // per-node edge bounds (wave-uniform scalars)
    int eb0 = ptr[nbase + 0], eb1 = ptr[nbase + 1], eb2 = ptr[nbase + 2],
        eb3 = ptr[nbase + 3], eb4 = ptr[nbase + 4];
    bool fixed16 = (eb1 - eb0 == 16) && (eb2 - eb1 == 16) &&
                   (eb3 - eb2 == 16) && (eb4 - eb3 == 16);

    float sums[4][8];

    if (fixed16) {
        // -------- fast path: 64 contiguous edges for this wave --------
        int vidx = idx[eb0 + lane];
        int vtyp = et[eb0 + lane];

        unsigned short xvA[16], xvB[16];

        // LOAD node nn into buffer; ACC from buffer
#define LOADN(buf, nn)                                                        \
        _Pragma("unroll")                                                     \
        for (int ee = 0; ee < 16; ++ee) {                                     \
            int src = __builtin_amdgcn_readlane(vidx, (nn) * 16 + ee);        \
            buf[ee] = xb[src * 64 + lane];                                    \
        }
#define ACCN(buf, nn)                                                         \
        {                                                                     \
            float s0=0.f,s1=0.f,s2=0.f,s3=0.f,s4=0.f,s5=0.f,s6=0.f,s7=0.f;    \
            _Pragma("unroll")                                                 \
            for (int ee = 0; ee < 16; ++ee) {                                 \
                int t = __builtin_amdgcn_readlane(vtyp, (nn) * 16 + ee);      \
                float v = bf2f(buf[ee]);                                      \
                if      (t == 0) s0 += v;                                     \
                else if (t == 1) s1 += v;                                     \
                else if (t == 2) s2 += v;                                     \
                else if (t == 3) s3 += v;                                     \
                else if (t == 4) s4 += v;                                     \
                else if (t == 5) s5 += v;                                     \
                else if (t == 6) s6 += v;                                     \
                else             s7 += v;                                     \
            }                                                                 \
            sums[nn][0]=s0; sums[nn][1]=s1; sums[nn][2]=s2; sums[nn][3]=s3;   \
            sums[nn][4]=s4; sums[nn][5]=s5; sums[nn][6]=s6; sums[nn][7]=s7;   \
        }

        LOADN(xvA, 0);
        LOADN(xvB, 1);
        ACCN(xvA, 0);
        LOADN(xvA, 2);
        ACCN(xvB, 1);
        LOADN(xvB, 3);
        ACCN(xvA, 2);
        ACCN(xvB, 3);
#undef LOADN
#undef ACCN
    } else {
        // -------- generic path --------
        int l16 = lane & 15;
        int ebs[5] = {eb0, eb1, eb2, eb3, eb4};
        for (int nn = 0; nn < 4; ++nn) {
            int eb = ebs[nn], en = ebs[nn + 1];
            float s0=0.f,s1=0.f,s2=0.f,s3=0.f,s4=0.f,s5=0.f,s6=0.f,s7=0.f;
            for (int e = eb; e < en; e += 16) {
                int m = en - e; if (m > 16) m = 16;
                int vi = 0, vt = 0;
                if (l16 < m) { vi = idx[e + l16]; vt = et[e + l16]; }
                for (int ee = 0; ee < m; ++ee) {
                    int src = __builtin_amdgcn_readlane(vi, ee);
                    int t   = __builtin_amdgcn_readlane(vt, ee);
                    float v = bf2f(xb[src * 64 + lane]);
                    if      (t == 0) s0 += v;
                    else if (t == 1) s1 += v;
                    else if (t == 2) s2 += v;
                    else if (t == 3) s3 += v;
                    else if (t == 4) s4 += v;
                    else if (t == 5) s5 += v;
                    else if (t == 6) s6 += v;
                    else             s7 += v;
                }
            }
            sums[nn][0]=s0; sums[nn][1]=s1; sums[nn][2]=s2; sums[nn][3]=s3;
            sums[nn][4]=s4; sums[nn][5]=s5; sums[nn][6]=s6; sums[nn][7]=s7;
        }
    }

    // store 4 rows, k = ki*8 + r: lane(=ki) owns 8 consecutive k -> one 16B swizzled write
#pragma unroll
    for (int nn = 0; nn < 4; ++nn) {
        int row = wave * 4 + nn;
        bf16x8 pk;
#pragma unroll
        for (int r = 0; r < 8; ++r) pk[r] = (short)f2bf(sums[nn][r]);
        unsigned int byte = ((unsigned int)row * 1024u + (unsigned int)lane * 16u)
                            ^ (((unsigned int)(row & 7)) << 4);
        *reinterpret_cast<bf16x8*>(sb + byte) = pk;
    }
    __syncthreads();

    // ---------- MFMA phase: wave handles N-slice nt = wave ----------
    int nt = wave;
    f32x4 acc = {0.f,0.f,0.f,0.f};
    unsigned int arow  = (unsigned int)(lane & 15);
    unsigned int abase = arow * 1024u + (unsigned int)((lane >> 4) * 16);
    unsigned int axor  = (arow & 7u) << 4;
#pragma unroll 4
    for (int kt = 0; kt < 16; ++kt) {
        unsigned int abyte = (abase + (unsigned int)kt * 64u) ^ axor;
        bf16x8 a = *reinterpret_cast<const bf16x8*>(sb + abyte);
        bf16x8 b = wf[(kt * 4 + nt) * 64 + lane];
        acc = __builtin_amdgcn_mfma_f32_16x16x32_bf16(a, b, acc, 0, 0, 0);
    }

    // ---------- epilogue: /deg, history overwrite, write both outputs (nontemporal) ----------
    int col   = nt * 16 + (lane & 15);
    int rquad = (lane >> 4) * 4;
#pragma unroll
    for (int j = 0; j < 4; ++j) {
        int node = n0 + rquad + j;
        float invd = 1.0f / (float)(ptr[node + 1] - ptr[node]);
        float v = acc[j] * invd;
        if (hmap[node] != -1) v = hbuf[node * 64 + col];
        __builtin_nontemporal_store(v, &out[node * 64 + col]);
        __builtin_nontemporal_store(v, &out[NNODE * 64 + node * 64 + col]);
    }
}

extern "C" void kernel_launch(void* const* d_in, const int* in_sizes, int n_in,
                              void* d_out, int out_size, void* d_ws, size_t ws_size,
                              hipStream_t stream) {
    (void)in_sizes; (void)n_in; (void)out_size; (void)ws_size;
    const float* x    = (const float*)d_in[0];
    const float* W    = (const float*)d_in[1];
    const int*   ptr  = (const int*)d_in[2];
    const int*   idx  = (const int*)d_in[3];
    const int*   et   = (const int*)d_in[4];
    const int*   hmap = (const int*)d_in[6];
    const float* hbuf = (const float*)d_in[7];
    float* out = (float*)d_out;

    unsigned short* xb = (unsigned short*)d_ws;                                     // 12.8 MB
    unsigned short* wfu = (unsigned short*)((char*)d_ws + (size_t)NNODE * CIN * 2); // 64 KB

    k_prep_x<<<dim3((NNODE * CIN / 4 + 255) / 256), dim3(256), 0, stream>>>(x, xb);
    k_prep_w<<<dim3(16), dim3(256), 0, stream>>>(W, wfu);
    k_main<<<dim3(NGRP), dim3(256), 0, stream>>>(
        xb, (const bf16x8*)wfu, ptr, idx, et, hmap, hbuf, out);
}